// Round 18
// baseline (147.396 us; speedup 1.0000x reference)
//
#include <hip/hip_runtime.h>
#include <math.h>

#define B_DIM 8
#define S_DIM 4096
#define D_DIM 1024
#define N_DIM 16
#define ROWS (B_DIM * S_DIM)          // 32768

#define CHUNK_L 32
#define WARM 64
#define STEPS (CHUNK_L + WARM)        // 96
#define NCHAIN (B_DIM * (S_DIM / CHUNK_L))   // 1024 chains

#define KSPLIT 8
#define KB_K 128                      // k per block
#define RPB 256                       // rows per block (1 per thread)
#define XB_BLOCKS ((ROWS / RPB) * KSPLIT)   // 128 * 8 = 1024
#define CW_BLOCKS ((N_DIM * D_DIM) / 256)   // 64

typedef float f32x4 __attribute__((ext_vector_type(4)));

// ---------------------------------------------------------------------------
// Kernel 1 (fused):
//  blocks [0,1024): partial xb GEMM with ZERO DS-pipe use (the per-CU DS
//  pipe, shared by 4 SIMDs, was the binding constraint in R6/R12/R17:
//  FMA:DS must exceed 24:1; B-broadcast-from-LDS can never achieve that at
//  N=16). Thread owns 1 row x all 16 n: x read ONCE as row-contiguous
//  float4s straight to VGPR (k_diag pattern, 5.4 TB/s proven, FETCH-exact);
//  B read per-lane from GLOBAL — same address across the wave -> TA/L1
//  broadcast (B slice 8KB, L1-resident), B:FMA = 1:4 -> TA ~14us < HBM 21.
//  ksplit 8 -> 1024 blocks = 4/CU = 16 waves/CU TLP (covers latency the
//  k_diag way; no manual pipelining — compiler shredded every attempt).
//  blocks [1024,1088): CW[n][d] = sum_k C[n][k]*W[d][k]  (round-1 proven).
// ---------------------------------------------------------------------------
__global__ __launch_bounds__(256) void k_xbcw(const float* __restrict__ x,
                                              const float* __restrict__ Bm,
                                              float* __restrict__ parts,
                                              const float* __restrict__ C,
                                              const float* __restrict__ W,
                                              float* __restrict__ CW) {
    const int t = threadIdx.x;
    if (blockIdx.x >= XB_BLOCKS) {
        // ---- CW part ----
        int u = (blockIdx.x - XB_BLOCKS) * 256 + t;
        int d = u >> 4;
        int n = u & 15;
        const float* crow = C + n * D_DIM;
        const float* wrow = W + (size_t)d * D_DIM;
        float acc = 0.f;
#pragma unroll 4
        for (int k = 0; k < D_DIM; k += 4) {
            float4 c4 = *(const float4*)(crow + k);
            float4 w4 = *(const float4*)(wrow + k);
            acc = fmaf(c4.x, w4.x, acc);
            acc = fmaf(c4.y, w4.y, acc);
            acc = fmaf(c4.z, w4.z, acc);
            acc = fmaf(c4.w, w4.w, acc);
        }
        CW[n * D_DIM + d] = acc;
        return;
    }
    // ---- xb partial: row = rt*256 + t, k in [ks*128, ks*128+128) ----
    const int rt = blockIdx.x >> 3;
    const int ks = blockIdx.x & 7;
    const int row = rt * RPB + t;
    const int k0 = ks * KB_K;
    const float* xr = x + (size_t)row * D_DIM + k0;
    const float* bp = Bm + (size_t)k0 * N_DIM;

    f32x4 aA = {0.f, 0.f, 0.f, 0.f};
    f32x4 aB = {0.f, 0.f, 0.f, 0.f};
    f32x4 aC = {0.f, 0.f, 0.f, 0.f};
    f32x4 aD = {0.f, 0.f, 0.f, 0.f};

#pragma unroll 8
    for (int g = 0; g < KB_K / 4; ++g) {       // 32 groups of 4 k
        f32x4 xq = *(const f32x4*)(xr + g * 4);
#pragma unroll
        for (int j = 0; j < 4; ++j) {
            const float xv = xq[j];
            const float* bk = bp + (g * 4 + j) * N_DIM;
            f32x4 b0 = *(const f32x4*)(bk + 0);
            f32x4 b1 = *(const f32x4*)(bk + 4);
            f32x4 b2 = *(const f32x4*)(bk + 8);
            f32x4 b3 = *(const f32x4*)(bk + 12);
            aA[0] = fmaf(xv, b0[0], aA[0]); aA[1] = fmaf(xv, b0[1], aA[1]);
            aA[2] = fmaf(xv, b0[2], aA[2]); aA[3] = fmaf(xv, b0[3], aA[3]);
            aB[0] = fmaf(xv, b1[0], aB[0]); aB[1] = fmaf(xv, b1[1], aB[1]);
            aB[2] = fmaf(xv, b1[2], aB[2]); aB[3] = fmaf(xv, b1[3], aB[3]);
            aC[0] = fmaf(xv, b2[0], aC[0]); aC[1] = fmaf(xv, b2[1], aC[1]);
            aC[2] = fmaf(xv, b2[2], aC[2]); aC[3] = fmaf(xv, b2[3], aC[3]);
            aD[0] = fmaf(xv, b3[0], aD[0]); aD[1] = fmaf(xv, b3[1], aD[1]);
            aD[2] = fmaf(xv, b3[2], aD[2]); aD[3] = fmaf(xv, b3[3], aD[3]);
        }
    }

    float* op = parts + (size_t)ks * ROWS * N_DIM + (size_t)row * N_DIM;
    *(f32x4*)(op + 0) = aA;
    *(f32x4*)(op + 4) = aB;
    *(f32x4*)(op + 8) = aC;
    *(f32x4*)(op + 12) = aD;
}

// ---------------------------------------------------------------------------
// Kernel 1b: xb = sum of 8 k-split partials (sequential order, determ.)
// ---------------------------------------------------------------------------
__global__ __launch_bounds__(256) void k_red(const float* __restrict__ parts,
                                             float* __restrict__ xb) {
    int i = (blockIdx.x * 256 + threadIdx.x) * 4;
    const size_t Q = (size_t)ROWS * N_DIM;
    float4 s = *(const float4*)(parts + i);
#pragma unroll
    for (int q = 1; q < KSPLIT; ++q) {
        float4 v = *(const float4*)(parts + (size_t)q * Q + i);
        s.x += v.x; s.y += v.y; s.z += v.z; s.w += v.w;
    }
    *(float4*)(xb + i) = s;
}

// ---------------------------------------------------------------------------
// Kernel 2: chunked scan (round-6 proven, UNCHANGED)
// ---------------------------------------------------------------------------
__global__ __launch_bounds__(64) void k_scan(const float* __restrict__ xb,
                                             const float* __restrict__ A,
                                             float* __restrict__ hs) {
    const int tid = threadIdx.x;
    const int n = tid & 15;
    const int base4 = (tid & 48) * 4;

    const int chain = blockIdx.x * 4 + (tid >> 4);
    const int b = chain >> 7;
    const int chunk = chain & 127;
    const int t0 = chunk * CHUNK_L - WARM;

    float Ar[16];
#pragma unroll
    for (int m4 = 0; m4 < 16; m4 += 4) {
        float4 v = *(const float4*)(A + n * 16 + m4);
        Ar[m4 + 0] = v.x; Ar[m4 + 1] = v.y; Ar[m4 + 2] = v.z; Ar[m4 + 3] = v.w;
    }

    const float* xp = xb + (size_t)b * S_DIM * N_DIM + n;
    float* hp = hs + (size_t)b * S_DIM * N_DIM + n;

    float ring[8];
#pragma unroll
    for (int i = 0; i < 8; ++i) {
        int tt = t0 + i;
        ring[i] = (tt >= 0) ? xp[(size_t)tt * N_DIM] : 0.f;
    }

    float h = 0.f;
    for (int tr0 = 0; tr0 < STEPS; tr0 += 8) {
#pragma unroll
        for (int j = 0; j < 8; ++j) {
            const int tr = tr0 + j;
            const float xv = ring[j];
            const int hbits = __float_as_int(h);
            int hm[16];
#pragma unroll
            for (int m = 0; m < 16; ++m)
                hm[m] = __builtin_amdgcn_ds_bpermute(base4 + m * 4, hbits);
            float acc0 = xv, acc1 = 0.f;
#pragma unroll
            for (int m = 0; m < 8; ++m) {
                acc0 = fmaf(Ar[m], __int_as_float(hm[m]), acc0);
                acc1 = fmaf(Ar[m + 8], __int_as_float(hm[m + 8]), acc1);
            }
            float g = acc0 + acc1;
            float ax = fabsf(g);
            float e = __expf(2.f * ax);
            float tv = 1.f - 2.f / (e + 1.f);
            h = (g < 0.f) ? -tv : tv;
            if (tr >= WARM)
                hp[(size_t)(t0 + tr) * N_DIM] = h;
            int tt = t0 + tr + 8;
            if (tr + 8 < STEPS)
                ring[j] = (tt >= 0) ? xp[(size_t)tt * N_DIM] : 0.f;
        }
    }
}

// ---------------------------------------------------------------------------
// Kernel 3: out[r][d] = sum_n hs[r][n] * CW[n][d] + bias[d]  (round-1 proven)
// ---------------------------------------------------------------------------
__global__ __launch_bounds__(256) void k_out(const float* __restrict__ hs,
                                             const float* __restrict__ CW,
                                             const float* __restrict__ bias,
                                             float* __restrict__ out) {
    const int t = threadIdx.x;
    const int d0 = t * 4;
    const int row0 = blockIdx.x * 32;
    float4 cw[16];
#pragma unroll
    for (int nn = 0; nn < 16; ++nn)
        cw[nn] = *(const float4*)(CW + nn * D_DIM + d0);
    float4 b4 = *(const float4*)(bias + d0);

    for (int r = row0; r < row0 + 32; ++r) {
        const float4* hp = (const float4*)(hs + (size_t)r * N_DIM);
        float4 h0 = hp[0], h1 = hp[1], h2 = hp[2], h3 = hp[3];
        float hv[16] = {h0.x, h0.y, h0.z, h0.w, h1.x, h1.y, h1.z, h1.w,
                        h2.x, h2.y, h2.z, h2.w, h3.x, h3.y, h3.z, h3.w};
        float4 acc = b4;
#pragma unroll
        for (int nn = 0; nn < 16; ++nn) {
            acc.x = fmaf(hv[nn], cw[nn].x, acc.x);
            acc.y = fmaf(hv[nn], cw[nn].y, acc.y);
            acc.z = fmaf(hv[nn], cw[nn].z, acc.z);
            acc.w = fmaf(hv[nn], cw[nn].w, acc.w);
        }
        *(float4*)(out + (size_t)r * D_DIM + d0) = acc;
    }
}

// ---------------------------------------------------------------------------
extern "C" void kernel_launch(void* const* d_in, const int* in_sizes, int n_in,
                              void* d_out, int out_size, void* d_ws,
                              size_t ws_size, hipStream_t stream) {
    const float* x    = (const float*)d_in[0];   // [8,4096,1024]
    const float* A    = (const float*)d_in[1];   // [16,16]
    const float* Bm   = (const float*)d_in[2];   // [1024,16]
    const float* C    = (const float*)d_in[3];   // [16,1024]
    const float* W    = (const float*)d_in[4];   // [1024,1024]
    const float* bias = (const float*)d_in[5];   // [1024]
    float* out = (float*)d_out;

    float* ws = (float*)d_ws;
    float* xb    = ws;                         // 524288 floats
    float* hs    = ws + 524288;                // 524288
    float* CW    = ws + 1048576;               // 16384
    float* parts = ws + 1064960;               // 8 * 524288

    k_xbcw<<<dim3(XB_BLOCKS + CW_BLOCKS), dim3(256), 0, stream>>>(
        x, Bm, parts, C, W, CW);
    k_red<<<dim3(ROWS * N_DIM / 1024), dim3(256), 0, stream>>>(parts, xb);
    k_scan<<<dim3(NCHAIN / 4), dim3(64), 0, stream>>>(xb, A, hs);
    k_out<<<dim3(ROWS / 32), dim3(256), 0, stream>>>(hs, CW, bias, out);
}